// Round 2
// baseline (557.012 us; speedup 1.0000x reference)
//
#include <hip/hip_runtime.h>
#include <hip/hip_bf16.h>

// Problem constants
constexpr int B  = 2;
constexpr int S  = 2048;
constexpr int E  = 1024;
constexpr int H  = 16;
constexpr int DK = 64;
constexpr int M  = B * S;   // 4096 rows of x
constexpr int N3 = 3 * E;   // 3072 = stacked [Wk; Wv; Wq] rows

using bf16x8 = __attribute__((ext_vector_type(8))) __bf16;
using bf16x4 = __attribute__((ext_vector_type(4))) __bf16;
using f32x4  = __attribute__((ext_vector_type(4))) float;

// ---- async global->LDS, 16B per lane. LDS dest must be wave-uniform base;
// lane i's data lands at base + i*16 (m97/m104-verified semantics). ----
__device__ __forceinline__ void async16(__bf16* lds, const __bf16* g) {
    __builtin_amdgcn_global_load_lds(
        (const __attribute__((address_space(1))) void*)g,
        (__attribute__((address_space(3))) void*)lds, 16, 0, 0);
}

// ================= fast path: cvt + single fused QKV GEMM =================

// Convert x (4M floats) and Wk|Wv|Wq (3x1M floats) to bf16; W's stacked into wall.
__global__ __launch_bounds__(256)
void cvt_kernel(const float* __restrict__ x, const float* __restrict__ Wk,
                const float* __restrict__ Wv, const float* __restrict__ Wq,
                __bf16* __restrict__ xb, __bf16* __restrict__ wall) {
    const long i4 = (long)blockIdx.x * 256 + threadIdx.x;  // one float4 each
    const long e  = i4 * 4;
    const float* src;
    __bf16* dst;
    if (e < (long)M * E) { src = x + e; dst = xb + e; }
    else {
        const long e2 = e - (long)M * E;
        const int which = (int)(e2 >> 20);            // 1M elems per W
        const long off  = e2 & ((1L << 20) - 1);
        src = (which == 0 ? Wk : which == 1 ? Wv : Wq) + off;
        dst = wall + e2;
    }
    float4 f = *reinterpret_cast<const float4*>(src);
    bf16x4 o;
    o[0] = (__bf16)f.x; o[1] = (__bf16)f.y; o[2] = (__bf16)f.z; o[3] = (__bf16)f.w;
    *reinterpret_cast<bf16x4*>(dst) = o;
}

// C[4096,3072] = xb @ wall^T, epilogue routes cols: [0,1024)->K, [1024,2048)->V^T,
// [2048,3072)->Q=cos(.+theta)/8. 128x128 tile, BK=32, global_load_lds staging.
__global__ __launch_bounds__(256)
void qkv_gemm(const __bf16* __restrict__ xb, const __bf16* __restrict__ wall,
              const float* __restrict__ theta, __bf16* __restrict__ k_ws,
              __bf16* __restrict__ v_ws, __bf16* __restrict__ q_ws) {
    __shared__ __align__(1024) __bf16 As[128 * 32];
    __shared__ __align__(1024) __bf16 Bs[128 * 32];

    const int t    = threadIdx.x;
    const int lane = t & 63;
    const int w    = t >> 6;
    const int quad = lane >> 4;
    const int l16  = lane & 15;
    const int wm   = w >> 1, wn = w & 1;           // 2x2 wave grid, 64x64 each
    const int mbase = blockIdx.y * 128;
    const int nbase = blockIdx.x * 128;

    f32x4 acc[4][4];
    #pragma unroll
    for (int i = 0; i < 4; i++)
        #pragma unroll
        for (int j = 0; j < 4; j++)
            acc[i][j] = f32x4{0.f, 0.f, 0.f, 0.f};

    const int arow = t >> 2;        // 0..63 (row within 64-row stage chunk)
    const int achk = t & 3;         // which 8-col chunk of BK=32

    for (int kk = 0; kk < E; kk += 32) {
        __syncthreads();   // previous iter's frag reads done before overwrite
        #pragma unroll
        for (int c = 0; c < 2; c++) {
            async16(&As[(c * 256 + w * 64) * 8],
                    xb + (long)(mbase + c * 64 + arow) * E + kk + achk * 8);
            async16(&Bs[(c * 256 + w * 64) * 8],
                    wall + (long)(nbase + c * 64 + arow) * E + kk + achk * 8);
        }
        asm volatile("s_waitcnt vmcnt(0)" ::: "memory");
        __syncthreads();

        bf16x8 a[4], b[4];
        #pragma unroll
        for (int i = 0; i < 4; i++)
            a[i] = *reinterpret_cast<const bf16x8*>(&As[(wm * 64 + i * 16 + l16) * 32 + quad * 8]);
        #pragma unroll
        for (int j = 0; j < 4; j++)
            b[j] = *reinterpret_cast<const bf16x8*>(&Bs[(wn * 64 + j * 16 + l16) * 32 + quad * 8]);
        #pragma unroll
        for (int i = 0; i < 4; i++)
            #pragma unroll
            for (int j = 0; j < 4; j++)
                acc[i][j] = __builtin_amdgcn_mfma_f32_16x16x32_bf16(a[i], b[j], acc[i][j], 0, 0, 0);
    }

    // Epilogue. C/D layout: row = quad*4+reg, col = lane&15 (m89/m91).
    const int region = nbase >> 10;       // block-uniform: 0=K 1=V 2=Q
    float th[4];
    if (region == 2) {
        #pragma unroll
        for (int j = 0; j < 4; j++) th[j] = theta[j * 16 + l16];  // d = j*16+l16
    }
    #pragma unroll
    for (int i = 0; i < 4; i++) {
        const int row0 = mbase + wm * 64 + i * 16 + quad * 4;
        #pragma unroll
        for (int j = 0; j < 4; j++) {
            const int cir = (nbase & 1023) + wn * 64 + j * 16 + l16;
            const int h = cir >> 6, d = cir & 63;
            #pragma unroll
            for (int r = 0; r < 4; r++) {
                const int row = row0 + r;
                const int bb = row >> 11, s = row & 2047;
                const float v = acc[i][j][r];
                if (region == 2)
                    q_ws[((long)(bb * H + h) * S + s) * DK + d] = (__bf16)(cosf(v + th[j]) * 0.125f);
                else if (region == 1)
                    v_ws[((long)(bb * H + h) * DK + d) * S + s] = (__bf16)v;
                else
                    k_ws[((long)(bb * H + h) * S + s) * DK + d] = (__bf16)v;
            }
        }
    }
}

// ============== fallback proj (round-1, used only if ws too small) ==============
__device__ inline bf16x8 cvt_frag(const float* __restrict__ p) {
    float4 f0 = *reinterpret_cast<const float4*>(p);
    float4 f1 = *reinterpret_cast<const float4*>(p + 4);
    bf16x8 r;
    r[0] = (__bf16)f0.x; r[1] = (__bf16)f0.y; r[2] = (__bf16)f0.z; r[3] = (__bf16)f0.w;
    r[4] = (__bf16)f1.x; r[5] = (__bf16)f1.y; r[6] = (__bf16)f1.z; r[7] = (__bf16)f1.w;
    return r;
}

template <int MODE>
__global__ __launch_bounds__(256)
void proj_kernel(const float* __restrict__ x, const float* __restrict__ W,
                 const float* __restrict__ theta, __bf16* __restrict__ out) {
    const int lane = threadIdx.x & 63;
    const int w    = threadIdx.x >> 6;
    const int quad = lane >> 4;
    const int l16  = lane & 15;
    const int mbase = blockIdx.y * 128 + w * 32;
    const int nbase = blockIdx.x * 128;

    f32x4 acc[2][8];
    #pragma unroll
    for (int i = 0; i < 2; i++)
        #pragma unroll
        for (int j = 0; j < 8; j++)
            acc[i][j] = f32x4{0.f, 0.f, 0.f, 0.f};

    float th[4];
    if (MODE == 2) {
        #pragma unroll
        for (int j = 0; j < 4; j++) th[j] = theta[j * 16 + l16];
    }

    for (int kk = 0; kk < E; kk += 32) {
        bf16x8 a[2], b[8];
        #pragma unroll
        for (int mt = 0; mt < 2; mt++)
            a[mt] = cvt_frag(x + (long)(mbase + mt * 16 + l16) * E + kk + quad * 8);
        #pragma unroll
        for (int nt = 0; nt < 8; nt++)
            b[nt] = cvt_frag(W + (long)(nbase + nt * 16 + l16) * E + kk + quad * 8);
        #pragma unroll
        for (int mt = 0; mt < 2; mt++)
            #pragma unroll
            for (int nt = 0; nt < 8; nt++)
                acc[mt][nt] = __builtin_amdgcn_mfma_f32_16x16x32_bf16(a[mt], b[nt], acc[mt][nt], 0, 0, 0);
    }
    #pragma unroll
    for (int mt = 0; mt < 2; mt++) {
        const int row0 = mbase + mt * 16 + quad * 4;
        #pragma unroll
        for (int nt = 0; nt < 8; nt++) {
            const int col = nbase + nt * 16 + l16;
            const int h = col >> 6, d = col & 63;
            #pragma unroll
            for (int r = 0; r < 4; r++) {
                const int row = row0 + r;
                const int bb = row >> 11, s = row & 2047;
                float v = acc[mt][nt][r];
                if (MODE == 2) v = cosf(v + th[nt & 3]) * 0.125f;
                long idx;
                if (MODE == 1) idx = ((long)(bb * H + h) * DK + d) * S + s;
                else           idx = ((long)(bb * H + h) * S + s) * DK + d;
                out[idx] = (__bf16)v;
            }
        }
    }
}

// ======================= attention (v2) =======================
// grid (S/64, B*H), 256 thr = 4 waves; wave owns 16 q-rows -> 4096 waves
// (16 waves/CU). Fixed-point softmax: scores bounded (|q|<=1/8 => |s|<~4),
// so no max-tracking, no rescale; l reduced once in epilogue. p_lds stride
// 72 bf16 (144B): <=2-way write conflicts (free, m136), 16B-aligned b128 reads.
__global__ __launch_bounds__(256)
void attn_kernel(const __bf16* __restrict__ q_ws, const __bf16* __restrict__ k_ws,
                 const __bf16* __restrict__ v_ws, float* __restrict__ out) {
    __shared__ __align__(16) __bf16 p_lds[4][16][72];

    const int lane = threadIdx.x & 63;
    const int w    = threadIdx.x >> 6;
    const int quad = lane >> 4;
    const int l16  = lane & 15;
    const int bh    = blockIdx.y;
    const int qbase = blockIdx.x * 64 + w * 16;

    const __bf16* qp = q_ws + (long)bh * S * DK;
    const __bf16* kp = k_ws + (long)bh * S * DK;
    const __bf16* vp = v_ws + (long)bh * DK * S;  // [DK][S]

    bf16x8 aq[2];
    #pragma unroll
    for (int ks = 0; ks < 2; ks++)
        aq[ks] = *reinterpret_cast<const bf16x8*>(
            qp + (long)(qbase + l16) * DK + ks * 32 + quad * 8);

    f32x4 o[4];
    #pragma unroll
    for (int j = 0; j < 4; j++) o[j] = f32x4{0.f, 0.f, 0.f, 0.f};
    float lsum[4] = {0.f, 0.f, 0.f, 0.f};

    for (int kt = 0; kt < S; kt += 64) {
        f32x4 sacc[4];
        #pragma unroll
        for (int j = 0; j < 4; j++) sacc[j] = f32x4{0.f, 0.f, 0.f, 0.f};
        #pragma unroll
        for (int ks = 0; ks < 2; ks++) {
            bf16x8 bk[4];
            #pragma unroll
            for (int nt = 0; nt < 4; nt++)
                bk[nt] = *reinterpret_cast<const bf16x8*>(
                    kp + (long)(kt + nt * 16 + l16) * DK + ks * 32 + quad * 8);
            #pragma unroll
            for (int nt = 0; nt < 4; nt++)
                sacc[nt] = __builtin_amdgcn_mfma_f32_16x16x32_bf16(aq[ks], bk[nt], sacc[nt], 0, 0, 0);
        }
        // p = exp(s), accumulate per-lane row partials, stash bf16 p for PV.
        #pragma unroll
        for (int r = 0; r < 4; r++) {
            #pragma unroll
            for (int nt = 0; nt < 4; nt++) {
                const float p = __expf(sacc[nt][r]);
                lsum[r] += p;
                p_lds[w][quad * 4 + r][nt * 16 + l16] = (__bf16)p;
            }
        }
        #pragma unroll
        for (int ks = 0; ks < 2; ks++) {
            bf16x8 ap = *reinterpret_cast<const bf16x8*>(&p_lds[w][l16][ks * 32 + quad * 8]);
            bf16x8 bv[4];
            #pragma unroll
            for (int nd = 0; nd < 4; nd++)
                bv[nd] = *reinterpret_cast<const bf16x8*>(
                    vp + (long)(nd * 16 + l16) * S + kt + ks * 32 + quad * 8);
            #pragma unroll
            for (int nd = 0; nd < 4; nd++)
                o[nd] = __builtin_amdgcn_mfma_f32_16x16x32_bf16(ap, bv[nd], o[nd], 0, 0, 0);
        }
    }

    // epilogue: reduce l over the 16 lanes holding each row's columns
    const int b = bh >> 4, h = bh & 15;
    #pragma unroll
    for (int r = 0; r < 4; r++) {
        float l = lsum[r];
        #pragma unroll
        for (int off = 1; off < 16; off <<= 1) l += __shfl_xor(l, off, 16);
        const float inv = 1.0f / l;
        const int srow = qbase + quad * 4 + r;
        #pragma unroll
        for (int nd = 0; nd < 4; nd++)
            out[(long)(b * S + srow) * E + h * DK + nd * 16 + l16] = o[nd][r] * inv;
    }
}

extern "C" void kernel_launch(void* const* d_in, const int* in_sizes, int n_in,
                              void* d_out, int out_size, void* d_ws, size_t ws_size,
                              hipStream_t stream) {
    const float* x     = (const float*)d_in[0];
    const float* Wk    = (const float*)d_in[1];
    const float* Wv    = (const float*)d_in[2];
    const float* Wq    = (const float*)d_in[3];  // [H,DK,E] flat == [1024,1024]
    const float* theta = (const float*)d_in[4];
    float* out = (float*)d_out;

    // ws layout: q,k,v bf16 (8 MB each) [+ xb 8 MB + wall 6 MB on fast path]
    __bf16* q_ws = (__bf16*)d_ws;
    __bf16* k_ws = q_ws + (long)B * H * S * DK;
    __bf16* v_ws = k_ws + (long)B * H * S * DK;
    __bf16* xb   = v_ws + (long)B * H * S * DK;
    __bf16* wall = xb + (long)M * E;

    const size_t need = ((long)3 * B * H * S * DK + (long)M * E + (long)N3 * E) * 2;
    dim3 blk(256);
    if (ws_size >= need) {
        cvt_kernel<<<dim3(7168), blk, 0, stream>>>(x, Wk, Wv, Wq, xb, wall);
        qkv_gemm<<<dim3(N3 / 128, M / 128), blk, 0, stream>>>(xb, wall, theta, k_ws, v_ws, q_ws);
    } else {
        dim3 gp(E / 128, M / 128);
        proj_kernel<0><<<gp, blk, 0, stream>>>(x, Wk, nullptr, k_ws);
        proj_kernel<1><<<gp, blk, 0, stream>>>(x, Wv, nullptr, v_ws);
        proj_kernel<2><<<gp, blk, 0, stream>>>(x, Wq, theta, q_ws);
    }

    attn_kernel<<<dim3(S / 64, B * H), blk, 0, stream>>>(q_ws, k_ws, v_ws, out);
}

// Round 3
// 353.565 us; speedup vs baseline: 1.5754x; 1.5754x over previous
//
#include <hip/hip_runtime.h>
#include <hip/hip_bf16.h>

// Problem constants
constexpr int B  = 2;
constexpr int S  = 2048;
constexpr int E  = 1024;
constexpr int H  = 16;
constexpr int DK = 64;
constexpr int M  = B * S;            // 4096 rows of x
constexpr int N3 = 3 * E;            // stacked [Wk; Wv; Wq]
constexpr long RSZ = (long)B * H * S * DK;  // 4.19M elems, one output region

using bf16x8 = __attribute__((ext_vector_type(8))) __bf16;
using bf16x4 = __attribute__((ext_vector_type(4))) __bf16;
using f32x4  = __attribute__((ext_vector_type(4))) float;

// async global->LDS, 16B/lane; LDS base wave-uniform, lane i lands at +i*16.
__device__ __forceinline__ void async16(__bf16* lds, const __bf16* g) {
    __builtin_amdgcn_global_load_lds(
        (const __attribute__((address_space(1))) void*)g,
        (__attribute__((address_space(3))) void*)lds, 16, 0, 0);
}

// ---------------- cvt: x and stacked W's -> bf16 ----------------
__global__ __launch_bounds__(256)
void cvt_kernel(const float* __restrict__ x, const float* __restrict__ Wk,
                const float* __restrict__ Wv, const float* __restrict__ Wq,
                __bf16* __restrict__ xb, __bf16* __restrict__ wall) {
    const long e = ((long)blockIdx.x * 256 + threadIdx.x) * 4;
    const float* src;
    __bf16* dst;
    if (e < (long)M * E) { src = x + e; dst = xb + e; }
    else {
        const long e2 = e - (long)M * E;
        const int which = (int)(e2 >> 20);
        const long off  = e2 & ((1L << 20) - 1);
        src = (which == 0 ? Wk : which == 1 ? Wv : Wq) + off;
        dst = wall + e2;
    }
    float4 f = *reinterpret_cast<const float4*>(src);
    bf16x4 o;
    o[0] = (__bf16)f.x; o[1] = (__bf16)f.y; o[2] = (__bf16)f.z; o[3] = (__bf16)f.w;
    *reinterpret_cast<bf16x4*>(dst) = o;
}

// ---------------- fused QKV GEMM (m97 structure) ----------------
// C[4096,3072] = xb @ wall^T. All regions stored row-major [B,H,S,DK]
// (coalesced 2B x 16-lane = 32B segments); region 2 gets cos(.+theta)/8.
// __launch_bounds__(256,2): VGPR cap 256 -> NO accumulator spill (R2's 72-VGPR
// build spilled acc, causing 1.4 GB of scratch write traffic).
__global__ __launch_bounds__(256, 2)
void qkv_gemm(const __bf16* __restrict__ xb, const __bf16* __restrict__ wall,
              const float* __restrict__ theta, __bf16* __restrict__ kvq) {
    __shared__ __align__(1024) __bf16 As[128 * 32];
    __shared__ __align__(1024) __bf16 Bs[128 * 32];

    const int t    = threadIdx.x;
    const int lane = t & 63;
    const int w    = t >> 6;
    const int quad = lane >> 4;
    const int l16  = lane & 15;
    const int wm   = w >> 1, wn = w & 1;      // 2x2 wave grid, 64x64 each
    const int mbase = blockIdx.y * 128;
    const int nbase = blockIdx.x * 128;

    f32x4 acc[4][4];
    #pragma unroll
    for (int i = 0; i < 4; i++)
        #pragma unroll
        for (int j = 0; j < 4; j++)
            acc[i][j] = f32x4{0.f, 0.f, 0.f, 0.f};

    const int arow = t >> 2;                  // staging row within 64-row chunk
    const int achk = t & 3;                   // 8-col chunk of BK=32
    const __bf16* ga = xb   + (long)(mbase + arow) * E + achk * 8;
    const __bf16* gb = wall + (long)(nbase + arow) * E + achk * 8;

    for (int kk = 0; kk < E; kk += 32) {
        __syncthreads();                      // frag reads of prev tile done
        #pragma unroll
        for (int c = 0; c < 2; c++) {
            async16(&As[(c * 256 + w * 64) * 8], ga + (long)c * 64 * E + kk);
            async16(&Bs[(c * 256 + w * 64) * 8], gb + (long)c * 64 * E + kk);
        }
        __syncthreads();                      // emits s_waitcnt vmcnt(0) + barrier

        bf16x8 a[4], b[4];
        #pragma unroll
        for (int i = 0; i < 4; i++)
            a[i] = *reinterpret_cast<const bf16x8*>(&As[(wm * 64 + i * 16 + l16) * 32 + quad * 8]);
        #pragma unroll
        for (int j = 0; j < 4; j++)
            b[j] = *reinterpret_cast<const bf16x8*>(&Bs[(wn * 64 + j * 16 + l16) * 32 + quad * 8]);
        #pragma unroll
        for (int i = 0; i < 4; i++)
            #pragma unroll
            for (int j = 0; j < 4; j++)
                acc[i][j] = __builtin_amdgcn_mfma_f32_16x16x32_bf16(a[i], b[j], acc[i][j], 0, 0, 0);
    }

    // Epilogue. C/D layout: row = quad*4+reg, col = lane&15 (m89/m91).
    const int region = nbase >> 10;           // block-uniform 0=K 1=V 2=Q
    __bf16* dst = kvq + region * RSZ;
    float th[4];
    if (region == 2) {
        #pragma unroll
        for (int j = 0; j < 4; j++) th[j] = theta[j * 16 + l16];
    }
    #pragma unroll
    for (int i = 0; i < 4; i++) {
        const int row0 = mbase + wm * 64 + i * 16 + quad * 4;
        #pragma unroll
        for (int j = 0; j < 4; j++) {
            const int cir = (nbase & 1023) + wn * 64 + j * 16 + l16;
            const int h = cir >> 6, d = cir & 63;
            #pragma unroll
            for (int r = 0; r < 4; r++) {
                const int row = row0 + r;
                const int bb = row >> 11, s = row & 2047;
                float v = acc[i][j][r];
                if (region == 2) v = cosf(v + th[j]) * 0.125f;  // fold 1/sqrt(DK)
                dst[((long)(bb * H + h) * S + s) * DK + d] = (__bf16)v;
            }
        }
    }
}

// ---------------- V transpose: [B,H,S,DK] -> [B,H,DK,S] ----------------
// 64x64 LDS tiles, XOR chunk swizzle -> conflict-free b128 in, scalar-gather
// out with 2-way-free banking; both global sides fully coalesced 16B.
__global__ __launch_bounds__(256)
void vtrans_kernel(const __bf16* __restrict__ vr, __bf16* __restrict__ vt) {
    __shared__ __bf16 tile[64 * 64];
    const int t = threadIdx.x;
    const int bh = blockIdx.y;
    const int sbase = blockIdx.x * 64;
    const __bf16* src = vr + ((long)bh * S + sbase) * DK;
    #pragma unroll
    for (int rr = 0; rr < 2; rr++) {
        const int idx = rr * 256 + t;
        const int sl = idx >> 3, dc = idx & 7;
        bf16x8 v = *reinterpret_cast<const bf16x8*>(src + sl * DK + dc * 8);
        const int dcs = dc ^ (sl >> 3);       // swizzle chunk by s bits 3..5
        *reinterpret_cast<bf16x8*>(&tile[sl * 64 + dcs * 8]) = v;
    }
    __syncthreads();
    __bf16* dstp = vt + (long)bh * DK * S + sbase;
    #pragma unroll
    for (int rr = 0; rr < 2; rr++) {
        const int idx = rr * 256 + t;
        const int dl = idx >> 3, sc = idx & 7;
        bf16x8 o;
        #pragma unroll
        for (int j = 0; j < 8; j++) {
            const int srow = sc * 8 + j;
            const int dcs = (dl >> 3) ^ (srow >> 3);
            o[j] = tile[srow * 64 + dcs * 8 + (dl & 7)];
        }
        *reinterpret_cast<bf16x8*>(dstp + (long)dl * S + sc * 8) = o;
    }
}

// ---------------- attention ----------------
// grid (S/128, B*H), 512 thr = 8 waves; wave owns 16 q-rows -> 4096 waves
// (16 waves/CU). Bounded scores (|q|<=1/8) => no max-tracking/rescale.
// p_lds stride 72: writes ~2-way (free), b128 reads bank-uniform.
__global__ __launch_bounds__(512, 2)
void attn_kernel(const __bf16* __restrict__ q_ws, const __bf16* __restrict__ k_ws,
                 const __bf16* __restrict__ v_ws, float* __restrict__ out) {
    __shared__ __align__(16) __bf16 p_lds[8][16][72];

    const int lane = threadIdx.x & 63;
    const int w    = threadIdx.x >> 6;        // 0..7
    const int quad = lane >> 4;
    const int l16  = lane & 15;
    const int bh    = blockIdx.y;
    const int qbase = blockIdx.x * 128 + w * 16;

    const __bf16* qp = q_ws + (long)bh * S * DK;
    const __bf16* kp = k_ws + (long)bh * S * DK;
    const __bf16* vp = v_ws + (long)bh * DK * S;   // [DK][S]

    bf16x8 aq[2];
    #pragma unroll
    for (int ks = 0; ks < 2; ks++)
        aq[ks] = *reinterpret_cast<const bf16x8*>(
            qp + (long)(qbase + l16) * DK + ks * 32 + quad * 8);

    f32x4 o[4];
    #pragma unroll
    for (int j = 0; j < 4; j++) o[j] = f32x4{0.f, 0.f, 0.f, 0.f};
    float lsum[4] = {0.f, 0.f, 0.f, 0.f};

    for (int kt = 0; kt < S; kt += 64) {
        f32x4 sacc[4];
        #pragma unroll
        for (int j = 0; j < 4; j++) sacc[j] = f32x4{0.f, 0.f, 0.f, 0.f};
        #pragma unroll
        for (int ks = 0; ks < 2; ks++) {
            bf16x8 bk[4];
            #pragma unroll
            for (int nt = 0; nt < 4; nt++)
                bk[nt] = *reinterpret_cast<const bf16x8*>(
                    kp + (long)(kt + nt * 16 + l16) * DK + ks * 32 + quad * 8);
            #pragma unroll
            for (int nt = 0; nt < 4; nt++)
                sacc[nt] = __builtin_amdgcn_mfma_f32_16x16x32_bf16(aq[ks], bk[nt], sacc[nt], 0, 0, 0);
        }
        #pragma unroll
        for (int r = 0; r < 4; r++) {
            #pragma unroll
            for (int nt = 0; nt < 4; nt++) {
                const float p = __expf(sacc[nt][r]);
                lsum[r] += p;
                p_lds[w][quad * 4 + r][nt * 16 + l16] = (__bf16)p;
            }
        }
        #pragma unroll
        for (int ks = 0; ks < 2; ks++) {
            bf16x8 ap = *reinterpret_cast<const bf16x8*>(&p_lds[w][l16][ks * 32 + quad * 8]);
            bf16x8 bv[4];
            #pragma unroll
            for (int nd = 0; nd < 4; nd++)
                bv[nd] = *reinterpret_cast<const bf16x8*>(
                    vp + (long)(nd * 16 + l16) * S + kt + ks * 32 + quad * 8);
            #pragma unroll
            for (int nd = 0; nd < 4; nd++)
                o[nd] = __builtin_amdgcn_mfma_f32_16x16x32_bf16(ap, bv[nd], o[nd], 0, 0, 0);
        }
    }

    const int b = bh >> 4, h = bh & 15;
    #pragma unroll
    for (int r = 0; r < 4; r++) {
        float l = lsum[r];
        #pragma unroll
        for (int off = 1; off < 16; off <<= 1) l += __shfl_xor(l, off, 16);
        const float inv = 1.0f / l;
        const int srow = qbase + quad * 4 + r;
        #pragma unroll
        for (int nd = 0; nd < 4; nd++)
            out[(long)(b * S + srow) * E + h * DK + nd * 16 + l16] = o[nd][r] * inv;
    }
}

// -------- fallback proj (direct fp32 loads, used only if ws too small) --------
__device__ inline bf16x8 cvt_frag(const float* __restrict__ p) {
    float4 f0 = *reinterpret_cast<const float4*>(p);
    float4 f1 = *reinterpret_cast<const float4*>(p + 4);
    bf16x8 r;
    r[0] = (__bf16)f0.x; r[1] = (__bf16)f0.y; r[2] = (__bf16)f0.z; r[3] = (__bf16)f0.w;
    r[4] = (__bf16)f1.x; r[5] = (__bf16)f1.y; r[6] = (__bf16)f1.z; r[7] = (__bf16)f1.w;
    return r;
}
template <int MODE>
__global__ __launch_bounds__(256, 2)
void proj_kernel(const float* __restrict__ x, const float* __restrict__ W,
                 const float* __restrict__ theta, __bf16* __restrict__ out) {
    const int lane = threadIdx.x & 63;
    const int w    = threadIdx.x >> 6;
    const int quad = lane >> 4;
    const int l16  = lane & 15;
    const int mbase = blockIdx.y * 128 + w * 32;
    const int nbase = blockIdx.x * 128;
    f32x4 acc[2][8];
    #pragma unroll
    for (int i = 0; i < 2; i++)
        #pragma unroll
        for (int j = 0; j < 8; j++) acc[i][j] = f32x4{0.f, 0.f, 0.f, 0.f};
    float th[4];
    if (MODE == 2) {
        #pragma unroll
        for (int j = 0; j < 4; j++) th[j] = theta[j * 16 + l16];
    }
    for (int kk = 0; kk < E; kk += 32) {
        bf16x8 a[2], b[8];
        #pragma unroll
        for (int mt = 0; mt < 2; mt++)
            a[mt] = cvt_frag(x + (long)(mbase + mt * 16 + l16) * E + kk + quad * 8);
        #pragma unroll
        for (int nt = 0; nt < 8; nt++)
            b[nt] = cvt_frag(W + (long)(nbase + nt * 16 + l16) * E + kk + quad * 8);
        #pragma unroll
        for (int mt = 0; mt < 2; mt++)
            #pragma unroll
            for (int nt = 0; nt < 8; nt++)
                acc[mt][nt] = __builtin_amdgcn_mfma_f32_16x16x32_bf16(a[mt], b[nt], acc[mt][nt], 0, 0, 0);
    }
    #pragma unroll
    for (int mt = 0; mt < 2; mt++) {
        const int row0 = mbase + mt * 16 + quad * 4;
        #pragma unroll
        for (int nt = 0; nt < 8; nt++) {
            const int col = nbase + nt * 16 + l16;
            const int h = col >> 6, d = col & 63;
            #pragma unroll
            for (int r = 0; r < 4; r++) {
                const int row = row0 + r;
                const int bb = row >> 11, s = row & 2047;
                float v = acc[mt][nt][r];
                if (MODE == 2) v = cosf(v + th[nt & 3]) * 0.125f;
                long idx;
                if (MODE == 1) idx = ((long)(bb * H + h) * DK + d) * S + s;  // V^T direct
                else           idx = ((long)(bb * H + h) * S + s) * DK + d;
                out[idx] = (__bf16)v;
            }
        }
    }
}

extern "C" void kernel_launch(void* const* d_in, const int* in_sizes, int n_in,
                              void* d_out, int out_size, void* d_ws, size_t ws_size,
                              hipStream_t stream) {
    const float* x     = (const float*)d_in[0];
    const float* Wk    = (const float*)d_in[1];
    const float* Wv    = (const float*)d_in[2];
    const float* Wq    = (const float*)d_in[3];
    const float* theta = (const float*)d_in[4];
    float* out = (float*)d_out;

    // ws: kvq[3*RSZ] | xb[M*E] (reused as v_t after gemm) | wall[N3*E]
    __bf16* kvq  = (__bf16*)d_ws;
    __bf16* xb   = kvq + 3 * RSZ;
    __bf16* wall = xb + (long)M * E;
    __bf16* k_ws = kvq;
    __bf16* vrow = kvq + RSZ;
    __bf16* q_ws = kvq + 2 * RSZ;
    __bf16* v_t  = xb;            // alias: xb dead after qkv_gemm

    const size_t need = (3 * RSZ + (long)M * E + (long)N3 * E) * 2;
    dim3 blk(256);
    if (ws_size >= need) {
        cvt_kernel<<<dim3(7168), blk, 0, stream>>>(x, Wk, Wv, Wq, xb, wall);
        qkv_gemm<<<dim3(N3 / 128, M / 128), blk, 0, stream>>>(xb, wall, theta, kvq);
        vtrans_kernel<<<dim3(S / 64, B * H), blk, 0, stream>>>(vrow, v_t);
    } else {
        // fallback: q,k,v_t packed in first 3 regions
        v_t = vrow;
        dim3 gp(E / 128, M / 128);
        proj_kernel<0><<<gp, blk, 0, stream>>>(x, Wk, nullptr, k_ws);
        proj_kernel<1><<<gp, blk, 0, stream>>>(x, Wv, nullptr, v_t);
        proj_kernel<2><<<gp, blk, 0, stream>>>(x, Wq, theta, q_ws);
    }

    attn_kernel<<<dim3(S / 128, B * H), dim3(512), 0, stream>>>(q_ws, k_ws, v_t, out);
}

// Round 4
// 190.531 us; speedup vs baseline: 2.9235x; 1.8557x over previous
//
#include <hip/hip_runtime.h>
#include <hip/hip_bf16.h>

// Problem constants
constexpr int B  = 2;
constexpr int S  = 2048;
constexpr int E  = 1024;
constexpr int H  = 16;
constexpr int DK = 64;
constexpr int M  = B * S;            // 4096 rows of x
constexpr int N3 = 3 * E;            // stacked [Wk; Wv; Wq]
constexpr long RSZ = (long)B * H * S * DK;  // one output region (4.19M elems)

using bf16x8 = __attribute__((ext_vector_type(8))) __bf16;
using bf16x4 = __attribute__((ext_vector_type(4))) __bf16;
using f32x4  = __attribute__((ext_vector_type(4))) float;

// async global->LDS, 16B/lane; LDS base wave-uniform, lane i lands at +i*16.
__device__ __forceinline__ void async16(__bf16* lds, const __bf16* g) {
    __builtin_amdgcn_global_load_lds(
        (const __attribute__((address_space(1))) void*)g,
        (__attribute__((address_space(3))) void*)lds, 16, 0, 0);
}

// ---------------- cvt: x and stacked W's -> bf16 ----------------
__global__ __launch_bounds__(256)
void cvt_kernel(const float* __restrict__ x, const float* __restrict__ Wk,
                const float* __restrict__ Wv, const float* __restrict__ Wq,
                __bf16* __restrict__ xb, __bf16* __restrict__ wall) {
    const long e = ((long)blockIdx.x * 256 + threadIdx.x) * 4;
    const float* src;
    __bf16* dst;
    if (e < (long)M * E) { src = x + e; dst = xb + e; }
    else {
        const long e2 = e - (long)M * E;
        const int which = (int)(e2 >> 20);
        const long off  = e2 & ((1L << 20) - 1);
        src = (which == 0 ? Wk : which == 1 ? Wv : Wq) + off;
        dst = wall + e2;
    }
    float4 f = *reinterpret_cast<const float4*>(src);
    bf16x4 o;
    o[0] = (__bf16)f.x; o[1] = (__bf16)f.y; o[2] = (__bf16)f.z; o[3] = (__bf16)f.w;
    *reinterpret_cast<bf16x4*>(dst) = o;
}

// ---------------- fused QKV GEMM (m97 structure, unchanged from R3) ----------------
__global__ __launch_bounds__(256, 2)
void qkv_gemm(const __bf16* __restrict__ xb, const __bf16* __restrict__ wall,
              const float* __restrict__ theta, __bf16* __restrict__ kvq) {
    __shared__ __align__(1024) __bf16 As[128 * 32];
    __shared__ __align__(1024) __bf16 Bs[128 * 32];

    const int t    = threadIdx.x;
    const int lane = t & 63;
    const int w    = t >> 6;
    const int quad = lane >> 4;
    const int l16  = lane & 15;
    const int wm   = w >> 1, wn = w & 1;      // 2x2 wave grid, 64x64 each
    const int mbase = blockIdx.y * 128;
    const int nbase = blockIdx.x * 128;

    f32x4 acc[4][4];
    #pragma unroll
    for (int i = 0; i < 4; i++)
        #pragma unroll
        for (int j = 0; j < 4; j++)
            acc[i][j] = f32x4{0.f, 0.f, 0.f, 0.f};

    const int arow = t >> 2;                  // staging row within 64-row chunk
    const int achk = t & 3;                   // 8-col chunk of BK=32
    const __bf16* ga = xb   + (long)(mbase + arow) * E + achk * 8;
    const __bf16* gb = wall + (long)(nbase + arow) * E + achk * 8;

    for (int kk = 0; kk < E; kk += 32) {
        __syncthreads();
        #pragma unroll
        for (int c = 0; c < 2; c++) {
            async16(&As[(c * 256 + w * 64) * 8], ga + (long)c * 64 * E + kk);
            async16(&Bs[(c * 256 + w * 64) * 8], gb + (long)c * 64 * E + kk);
        }
        __syncthreads();

        bf16x8 a[4], b[4];
        #pragma unroll
        for (int i = 0; i < 4; i++)
            a[i] = *reinterpret_cast<const bf16x8*>(&As[(wm * 64 + i * 16 + l16) * 32 + quad * 8]);
        #pragma unroll
        for (int j = 0; j < 4; j++)
            b[j] = *reinterpret_cast<const bf16x8*>(&Bs[(wn * 64 + j * 16 + l16) * 32 + quad * 8]);
        #pragma unroll
        for (int i = 0; i < 4; i++)
            #pragma unroll
            for (int j = 0; j < 4; j++)
                acc[i][j] = __builtin_amdgcn_mfma_f32_16x16x32_bf16(a[i], b[j], acc[i][j], 0, 0, 0);
    }

    const int region = nbase >> 10;           // block-uniform 0=K 1=V 2=Q
    __bf16* dst = kvq + region * RSZ;
    float th[4];
    if (region == 2) {
        #pragma unroll
        for (int j = 0; j < 4; j++) th[j] = theta[j * 16 + l16];
    }
    #pragma unroll
    for (int i = 0; i < 4; i++) {
        const int row0 = mbase + wm * 64 + i * 16 + quad * 4;
        #pragma unroll
        for (int j = 0; j < 4; j++) {
            const int cir = (nbase & 1023) + wn * 64 + j * 16 + l16;
            const int h = cir >> 6, d = cir & 63;
            #pragma unroll
            for (int r = 0; r < 4; r++) {
                const int row = row0 + r;
                const int bb = row >> 11, s = row & 2047;
                float v = acc[i][j][r];
                if (region == 2) v = cosf(v + th[j]) * 0.125f;  // fold 1/sqrt(DK)
                dst[((long)(bb * H + h) * S + s) * DK + d] = (__bf16)v;
            }
        }
    }
}

// ---------------- V transpose: [B,H,S,DK] -> [B,H,DK,S] ----------------
__global__ __launch_bounds__(256)
void vtrans_kernel(const __bf16* __restrict__ vr, __bf16* __restrict__ vt) {
    __shared__ __bf16 tile[64 * 64];
    const int t = threadIdx.x;
    const int bh = blockIdx.y;
    const int sbase = blockIdx.x * 64;
    const __bf16* src = vr + ((long)bh * S + sbase) * DK;
    #pragma unroll
    for (int rr = 0; rr < 2; rr++) {
        const int idx = rr * 256 + t;
        const int sl = idx >> 3, dc = idx & 7;
        bf16x8 v = *reinterpret_cast<const bf16x8*>(src + sl * DK + dc * 8);
        const int dcs = dc ^ (sl >> 3);
        *reinterpret_cast<bf16x8*>(&tile[sl * 64 + dcs * 8]) = v;
    }
    __syncthreads();
    __bf16* dstp = vt + (long)bh * DK * S + sbase;
    #pragma unroll
    for (int rr = 0; rr < 2; rr++) {
        const int idx = rr * 256 + t;
        const int dl = idx >> 3, sc = idx & 7;
        bf16x8 o;
        #pragma unroll
        for (int j = 0; j < 8; j++) {
            const int srow = sc * 8 + j;
            const int dcs = (dl >> 3) ^ (srow >> 3);
            o[j] = tile[srow * 64 + dcs * 8 + (dl & 7)];
        }
        *reinterpret_cast<bf16x8*>(dstp + (long)dl * S + sc * 8) = o;
    }
}

// ---------------- attention v3: LDS-staged K/V, 1-barrier pipeline ----------------
// grid (S/128, B*H) = 512 blocks, 256 thr = 4 waves; wave owns 32 q-rows.
// Per 64-key tile: K-tile 8KB + V-tile 8KB staged via global_load_lds into the
// double buffer NOT being read (stage issued after the barrier -> overlaps the
// whole compute phase; vmcnt(0) drain at the next barrier is then ~free).
// XOR chunk swizzle (pos = chunk ^ (row&7)) makes all ds_read_b128 frag reads
// 2-way (free, m136). lsum via ones-vector MFMA (no fmacs, no shuffle reduce).
// Bounded scores (|q|<=1/8) => no max-tracking/rescale (verified R1-R3).
__global__ __launch_bounds__(256, 2)
void attn_kernel(const __bf16* __restrict__ q_ws, const __bf16* __restrict__ k_ws,
                 const __bf16* __restrict__ v_ws, float* __restrict__ out) {
    __shared__ __align__(1024) __bf16 Ks[2][64 * 64];   // [key][d], swizzled
    __shared__ __align__(1024) __bf16 Vs[2][64 * 64];   // [d][key], swizzled
    __shared__ __align__(16)   __bf16 p_lds[4][32][72]; // per-wave P buffer

    const int lane = threadIdx.x & 63;
    const int w    = threadIdx.x >> 6;
    const int quad = lane >> 4;
    const int l16  = lane & 15;
    const int bh    = blockIdx.y;
    const int qbase = blockIdx.x * 128 + w * 32;

    const __bf16* qp = q_ws + (long)bh * S * DK;
    const __bf16* kp = k_ws + (long)bh * S * DK;
    const __bf16* vp = v_ws + (long)bh * DK * S;   // [DK][S]

    // staging lane decomposition: 8 rows x 8 chunks(16B) per wave-issue
    const int sr  = lane >> 3;          // row within 8-row group
    const int sc  = lane & 7;           // chunk position (LDS lands at +lane*16)
    const int scs = sc ^ sr;            // swizzled SOURCE chunk

    // Q A-frags, loaded once (A[m=l16][k=quad*8+j])
    bf16x8 aq[2][2];
    #pragma unroll
    for (int mt = 0; mt < 2; mt++)
        #pragma unroll
        for (int ks = 0; ks < 2; ks++)
            aq[mt][ks] = *reinterpret_cast<const bf16x8*>(
                qp + (long)(qbase + mt * 16 + l16) * DK + ks * 32 + quad * 8);

    bf16x8 vone;
    #pragma unroll
    for (int j = 0; j < 8; j++) vone[j] = (__bf16)1.0f;

    f32x4 o[2][4];
    #pragma unroll
    for (int i = 0; i < 2; i++)
        #pragma unroll
        for (int j = 0; j < 4; j++) o[i][j] = f32x4{0.f, 0.f, 0.f, 0.f};
    f32x4 ls[2] = {f32x4{0.f, 0.f, 0.f, 0.f}, f32x4{0.f, 0.f, 0.f, 0.f}};

    // prefetch tile 0 into buffer 0
    #pragma unroll
    for (int i = 0; i < 2; i++) {
        const int row = i * 32 + w * 8;                       // wave-uniform
        async16(&Ks[0][row * 64], kp + (long)(row + sr) * DK + scs * 8);
        async16(&Vs[0][row * 64], vp + (long)(row + sr) * S + scs * 8);
    }

    for (int it = 0; it < S / 64; it++) {
        const int cur = it & 1;
        __syncthreads();   // drains vmcnt(0): tile `cur` staged; prev reads done

        if (it + 1 < S / 64) {
            const int kt1 = (it + 1) * 64;
            #pragma unroll
            for (int i = 0; i < 2; i++) {
                const int row = i * 32 + w * 8;
                async16(&Ks[cur ^ 1][row * 64], kp + (long)(kt1 + row + sr) * DK + scs * 8);
                async16(&Vs[cur ^ 1][row * 64], vp + (long)(row + sr) * S + kt1 + scs * 8);
            }
        }

        // ---- S = Q K^T ----
        f32x4 sacc[2][4];
        #pragma unroll
        for (int i = 0; i < 2; i++)
            #pragma unroll
            for (int j = 0; j < 4; j++) sacc[i][j] = f32x4{0.f, 0.f, 0.f, 0.f};
        #pragma unroll
        for (int ks = 0; ks < 2; ks++) {
            bf16x8 bk[4];
            #pragma unroll
            for (int nt = 0; nt < 4; nt++)
                bk[nt] = *reinterpret_cast<const bf16x8*>(
                    &Ks[cur][(nt * 16 + l16) * 64 + ((ks * 4 + quad) ^ (l16 & 7)) * 8]);
            #pragma unroll
            for (int mt = 0; mt < 2; mt++)
                #pragma unroll
                for (int nt = 0; nt < 4; nt++)
                    sacc[mt][nt] = __builtin_amdgcn_mfma_f32_16x16x32_bf16(
                        aq[mt][ks], bk[nt], sacc[mt][nt], 0, 0, 0);
        }
        // ---- P = exp(S) -> per-wave LDS (C-layout -> A-layout round trip) ----
        #pragma unroll
        for (int mt = 0; mt < 2; mt++)
            #pragma unroll
            for (int r = 0; r < 4; r++)
                #pragma unroll
                for (int nt = 0; nt < 4; nt++)
                    p_lds[w][mt * 16 + quad * 4 + r][nt * 16 + l16] =
                        (__bf16)__expf(sacc[mt][nt][r]);
        // ---- O += P V ; l += P * ones ----
        #pragma unroll
        for (int ks = 0; ks < 2; ks++) {
            bf16x8 ap[2];
            #pragma unroll
            for (int mt = 0; mt < 2; mt++)
                ap[mt] = *reinterpret_cast<const bf16x8*>(
                    &p_lds[w][mt * 16 + l16][ks * 32 + quad * 8]);
            bf16x8 bv[4];
            #pragma unroll
            for (int nd = 0; nd < 4; nd++)
                bv[nd] = *reinterpret_cast<const bf16x8*>(
                    &Vs[cur][(nd * 16 + l16) * 64 + ((ks * 4 + quad) ^ (l16 & 7)) * 8]);
            #pragma unroll
            for (int mt = 0; mt < 2; mt++) {
                ls[mt] = __builtin_amdgcn_mfma_f32_16x16x32_bf16(ap[mt], vone, ls[mt], 0, 0, 0);
                #pragma unroll
                for (int nd = 0; nd < 4; nd++)
                    o[mt][nd] = __builtin_amdgcn_mfma_f32_16x16x32_bf16(
                        ap[mt], bv[nd], o[mt][nd], 0, 0, 0);
            }
        }
    }

    // ---- epilogue: out[b][s][h*64+d] = O / l ----
    const int b = bh >> 4, h = bh & 15;
    #pragma unroll
    for (int mt = 0; mt < 2; mt++) {
        #pragma unroll
        for (int r = 0; r < 4; r++) {
            const float inv = 1.0f / ls[mt][r];
            const int srow = qbase + mt * 16 + quad * 4 + r;
            #pragma unroll
            for (int nd = 0; nd < 4; nd++)
                out[(long)(b * S + srow) * E + h * DK + nd * 16 + l16] = o[mt][nd][r] * inv;
        }
    }
}

// -------- fallback proj (direct fp32 loads, used only if ws too small) --------
__device__ inline bf16x8 cvt_frag(const float* __restrict__ p) {
    float4 f0 = *reinterpret_cast<const float4*>(p);
    float4 f1 = *reinterpret_cast<const float4*>(p + 4);
    bf16x8 r;
    r[0] = (__bf16)f0.x; r[1] = (__bf16)f0.y; r[2] = (__bf16)f0.z; r[3] = (__bf16)f0.w;
    r[4] = (__bf16)f1.x; r[5] = (__bf16)f1.y; r[6] = (__bf16)f1.z; r[7] = (__bf16)f1.w;
    return r;
}
template <int MODE>
__global__ __launch_bounds__(256, 2)
void proj_kernel(const float* __restrict__ x, const float* __restrict__ W,
                 const float* __restrict__ theta, __bf16* __restrict__ out) {
    const int lane = threadIdx.x & 63;
    const int w    = threadIdx.x >> 6;
    const int quad = lane >> 4;
    const int l16  = lane & 15;
    const int mbase = blockIdx.y * 128 + w * 32;
    const int nbase = blockIdx.x * 128;
    f32x4 acc[2][8];
    #pragma unroll
    for (int i = 0; i < 2; i++)
        #pragma unroll
        for (int j = 0; j < 8; j++) acc[i][j] = f32x4{0.f, 0.f, 0.f, 0.f};
    float th[4];
    if (MODE == 2) {
        #pragma unroll
        for (int j = 0; j < 4; j++) th[j] = theta[j * 16 + l16];
    }
    for (int kk = 0; kk < E; kk += 32) {
        bf16x8 a[2], b[8];
        #pragma unroll
        for (int mt = 0; mt < 2; mt++)
            a[mt] = cvt_frag(x + (long)(mbase + mt * 16 + l16) * E + kk + quad * 8);
        #pragma unroll
        for (int nt = 0; nt < 8; nt++)
            b[nt] = cvt_frag(W + (long)(nbase + nt * 16 + l16) * E + kk + quad * 8);
        #pragma unroll
        for (int mt = 0; mt < 2; mt++)
            #pragma unroll
            for (int nt = 0; nt < 8; nt++)
                acc[mt][nt] = __builtin_amdgcn_mfma_f32_16x16x32_bf16(a[mt], b[nt], acc[mt][nt], 0, 0, 0);
    }
    #pragma unroll
    for (int mt = 0; mt < 2; mt++) {
        const int row0 = mbase + mt * 16 + quad * 4;
        #pragma unroll
        for (int nt = 0; nt < 8; nt++) {
            const int col = nbase + nt * 16 + l16;
            const int h = col >> 6, d = col & 63;
            #pragma unroll
            for (int r = 0; r < 4; r++) {
                const int row = row0 + r;
                const int bb = row >> 11, s = row & 2047;
                float v = acc[mt][nt][r];
                if (MODE == 2) v = cosf(v + th[nt & 3]) * 0.125f;
                long idx;
                if (MODE == 1) idx = ((long)(bb * H + h) * DK + d) * S + s;
                else           idx = ((long)(bb * H + h) * S + s) * DK + d;
                out[idx] = (__bf16)v;
            }
        }
    }
}

extern "C" void kernel_launch(void* const* d_in, const int* in_sizes, int n_in,
                              void* d_out, int out_size, void* d_ws, size_t ws_size,
                              hipStream_t stream) {
    const float* x     = (const float*)d_in[0];
    const float* Wk    = (const float*)d_in[1];
    const float* Wv    = (const float*)d_in[2];
    const float* Wq    = (const float*)d_in[3];
    const float* theta = (const float*)d_in[4];
    float* out = (float*)d_out;

    // ws: kvq[3*RSZ] | xb[M*E] (reused as v_t after gemm) | wall[N3*E]
    __bf16* kvq  = (__bf16*)d_ws;
    __bf16* xb   = kvq + 3 * RSZ;
    __bf16* wall = xb + (long)M * E;
    __bf16* k_ws = kvq;
    __bf16* vrow = kvq + RSZ;
    __bf16* q_ws = kvq + 2 * RSZ;
    __bf16* v_t  = xb;            // alias: xb dead after qkv_gemm

    const size_t need = (3 * RSZ + (long)M * E + (long)N3 * E) * 2;
    dim3 blk(256);
    if (ws_size >= need) {
        cvt_kernel<<<dim3(7168), blk, 0, stream>>>(x, Wk, Wv, Wq, xb, wall);
        qkv_gemm<<<dim3(N3 / 128, M / 128), blk, 0, stream>>>(xb, wall, theta, kvq);
        vtrans_kernel<<<dim3(S / 64, B * H), blk, 0, stream>>>(vrow, v_t);
    } else {
        v_t = vrow;
        dim3 gp(E / 128, M / 128);
        proj_kernel<0><<<gp, blk, 0, stream>>>(x, Wk, nullptr, k_ws);
        proj_kernel<1><<<gp, blk, 0, stream>>>(x, Wv, nullptr, v_t);
        proj_kernel<2><<<gp, blk, 0, stream>>>(x, Wq, theta, q_ws);
    }

    attn_kernel<<<dim3(S / 128, B * H), blk, 0, stream>>>(q_ws, k_ws, v_t, out);
}

// Round 5
// 185.983 us; speedup vs baseline: 2.9950x; 1.0245x over previous
//
#include <hip/hip_runtime.h>
#include <hip/hip_bf16.h>

// Problem constants
constexpr int B  = 2;
constexpr int S  = 2048;
constexpr int E  = 1024;
constexpr int H  = 16;
constexpr int DK = 64;
constexpr int M  = B * S;            // 4096 rows of x
constexpr int N3 = 3 * E;            // stacked [Wk; Wv; Wq]
constexpr long RSZ = (long)B * H * S * DK;  // one output region (4.19M elems)

using bf16x8 = __attribute__((ext_vector_type(8))) __bf16;
using bf16x4 = __attribute__((ext_vector_type(4))) __bf16;
using f32x4  = __attribute__((ext_vector_type(4))) float;

// async global->LDS, 16B/lane; LDS base wave-uniform, lane i lands at +i*16 B.
__device__ __forceinline__ void async16(__bf16* lds, const __bf16* g) {
    __builtin_amdgcn_global_load_lds(
        (const __attribute__((address_space(1))) void*)g,
        (__attribute__((address_space(3))) void*)lds, 16, 0, 0);
}

// ---------------- cvt: x and stacked W's -> bf16 ----------------
__global__ __launch_bounds__(256)
void cvt_kernel(const float* __restrict__ x, const float* __restrict__ Wk,
                const float* __restrict__ Wv, const float* __restrict__ Wq,
                __bf16* __restrict__ xb, __bf16* __restrict__ wall) {
    const long e = ((long)blockIdx.x * 256 + threadIdx.x) * 4;
    const float* src;
    __bf16* dst;
    if (e < (long)M * E) { src = x + e; dst = xb + e; }
    else {
        const long e2 = e - (long)M * E;
        const int which = (int)(e2 >> 20);
        const long off  = e2 & ((1L << 20) - 1);
        src = (which == 0 ? Wk : which == 1 ? Wv : Wq) + off;
        dst = wall + e2;
    }
    float4 f = *reinterpret_cast<const float4*>(src);
    bf16x4 o;
    o[0] = (__bf16)f.x; o[1] = (__bf16)f.y; o[2] = (__bf16)f.z; o[3] = (__bf16)f.w;
    *reinterpret_cast<bf16x4*>(dst) = o;
}

// ---------------- fused QKV GEMM v2 ----------------
// C[4096,3072] = xb @ wall^T. Single-barrier double-buffered staging (prefetch
// issued AFTER the barrier overlaps the whole compute phase — attn-v3 pattern).
// XOR chunk swizzle: LDS[row][p] = global[row][p ^ ((row>>1)&3)] -> frag
// ds_read_b128 is 2-way (free) instead of 8-way.
// Region epilogues: 0=K row-major, 2=Q cos(.+theta)/8 row-major,
// 1=V transposed in-LDS (aliasing the 32 KB staging buffers) -> coalesced V^T.
__global__ __launch_bounds__(256, 3)
void qkv_gemm(const __bf16* __restrict__ xb, const __bf16* __restrict__ wall,
              const float* __restrict__ theta, __bf16* __restrict__ kvq) {
    __shared__ __align__(1024) __bf16 smem[4 * 128 * 32];   // As0|As1|Bs0|Bs1 = 32 KB
    __bf16* tile = smem;                                    // epilogue alias: 128x128

    const int t    = threadIdx.x;
    const int lane = t & 63;
    const int w    = t >> 6;
    const int quad = lane >> 4;
    const int l16  = lane & 15;
    const int wm   = w >> 1, wn = w & 1;      // 2x2 wave grid, 64x64 each
    const int mbase = blockIdx.y * 128;
    const int nbase = blockIdx.x * 128;

    f32x4 acc[4][4];
    #pragma unroll
    for (int i = 0; i < 4; i++)
        #pragma unroll
        for (int j = 0; j < 4; j++)
            acc[i][j] = f32x4{0.f, 0.f, 0.f, 0.f};

    // staging: lane i covers row (i>>2), LDS chunk (i&3); source chunk swizzled
    const int srow = lane >> 2;
    const int srcc = (lane & 3) ^ ((lane >> 3) & 3);   // (i&3) ^ ((row>>1)&3)
    const __bf16* ga = xb   + (long)(mbase + srow) * E + srcc * 8;
    const __bf16* gb = wall + (long)(nbase + srow) * E + srcc * 8;

    const int csw = (l16 >> 1) & 3;                    // read-side swizzle term

    // prefetch tile 0 into buffer 0
    #pragma unroll
    for (int c = 0; c < 2; c++) {
        async16(smem +        (c * 64 + w * 16) * 32, ga + (long)(c * 64 + w * 16) * E);
        async16(smem + 8192 + (c * 64 + w * 16) * 32, gb + (long)(c * 64 + w * 16) * E);
    }

    for (int it = 0; it < E / 32; it++) {
        const int cur = it & 1;
        __syncthreads();    // drains vmcnt(0): tile cur staged; prev frag reads done

        if (it + 1 < E / 32) {
            const int kk1 = (it + 1) * 32;
            #pragma unroll
            for (int c = 0; c < 2; c++) {
                async16(smem + (cur ^ 1) * 4096 +        (c * 64 + w * 16) * 32,
                        ga + (long)(c * 64 + w * 16) * E + kk1);
                async16(smem + (cur ^ 1) * 4096 + 8192 + (c * 64 + w * 16) * 32,
                        gb + (long)(c * 64 + w * 16) * E + kk1);
            }
        }

        const __bf16* Asb = smem + cur * 4096;
        const __bf16* Bsb = smem + cur * 4096 + 8192;
        bf16x8 a[4], b[4];
        #pragma unroll
        for (int i = 0; i < 4; i++)
            a[i] = *reinterpret_cast<const bf16x8*>(
                &Asb[(wm * 64 + i * 16 + l16) * 32 + (quad ^ csw) * 8]);
        #pragma unroll
        for (int j = 0; j < 4; j++)
            b[j] = *reinterpret_cast<const bf16x8*>(
                &Bsb[(wn * 64 + j * 16 + l16) * 32 + (quad ^ csw) * 8]);
        #pragma unroll
        for (int i = 0; i < 4; i++)
            #pragma unroll
            for (int j = 0; j < 4; j++)
                acc[i][j] = __builtin_amdgcn_mfma_f32_16x16x32_bf16(a[i], b[j], acc[i][j], 0, 0, 0);
    }

    // Epilogue. C/D layout: row = quad*4+reg, col = lane&15 (m89/m91).
    const int region = nbase >> 10;           // block-uniform 0=K 1=V 2=Q
    const int bb = mbase >> 11;               // whole tile within one batch
    if (region == 1) {
        // ---- V: transpose C-tile in LDS, write V^T coalesced ----
        __syncthreads();                      // staging reads finished
        #pragma unroll
        for (int i = 0; i < 4; i++) {
            const int cchunk = wm * 8 + i * 2 + (quad >> 1);   // s_local>>3
            #pragma unroll
            for (int j = 0; j < 4; j++) {
                const int cirb = wn * 64 + j * 16 + l16;       // block-local col
                const int cs = cchunk ^ l16;                   // ^= (cirb&15)
                bf16x4 pk;
                #pragma unroll
                for (int r = 0; r < 4; r++) pk[r] = (__bf16)acc[i][j][r];
                *reinterpret_cast<bf16x4*>(&tile[cirb * 128 + cs * 8 + (quad & 1) * 4]) = pk;
            }
        }
        __syncthreads();
        const int h0 = (nbase & 1023) >> 6;
        __bf16* vt = kvq + RSZ;               // V^T region: [B,H,DK,S]
        #pragma unroll
        for (int p = 0; p < 8; p++) {
            const int dcol = p * 16 + (t >> 4);
            const int lc = t & 15;
            const int cs2 = lc ^ (dcol & 15);
            bf16x8 vv = *reinterpret_cast<const bf16x8*>(&tile[dcol * 128 + cs2 * 8]);
            const int hh = h0 + (dcol >> 6), d = dcol & 63;
            *reinterpret_cast<bf16x8*>(
                &vt[((long)(bb * H + hh) * DK + d) * S + (mbase & 2047) + lc * 8]) = vv;
        }
    } else {
        __bf16* dst = kvq + (region == 2 ? 2 * RSZ : 0);
        float th[4];
        if (region == 2) {
            #pragma unroll
            for (int j = 0; j < 4; j++) th[j] = theta[j * 16 + l16];
        }
        #pragma unroll
        for (int i = 0; i < 4; i++) {
            const int row0 = mbase + wm * 64 + i * 16 + quad * 4;
            #pragma unroll
            for (int j = 0; j < 4; j++) {
                const int cir = (nbase & 1023) + wn * 64 + j * 16 + l16;
                const int h = cir >> 6, d = cir & 63;
                #pragma unroll
                for (int r = 0; r < 4; r++) {
                    const int s = (row0 + r) & 2047;
                    float v = acc[i][j][r];
                    if (region == 2) v = cosf(v + th[j]) * 0.125f;  // fold 1/sqrt(DK)
                    dst[((long)(bb * H + h) * S + s) * DK + d] = (__bf16)v;
                }
            }
        }
    }
}

// ---------------- attention v4 ----------------
// grid (S/128, B*H), 256 thr = 4 waves; wave owns 32 q-rows. Single-barrier
// double-buffered K/V staging (R4-verified). P round-trip now stores the raw
// MFMA C-layout (p_c[slot][lane]): b16 stores are lane-linear (conflict-free),
// A-frag b128 reads hit 1 lane/bank. LDS 48 KB -> 3 blocks/CU at (256,3).
// Bounded scores (|q|<=1/8) => no max-tracking/rescale (verified R1-R4).
__global__ __launch_bounds__(256, 3)
void attn_kernel(const __bf16* __restrict__ q_ws, const __bf16* __restrict__ k_ws,
                 const __bf16* __restrict__ v_ws, float* __restrict__ out) {
    __shared__ __align__(1024) __bf16 Ks[2][64 * 64];   // [key][d], swizzled
    __shared__ __align__(1024) __bf16 Vs[2][64 * 64];   // [d][key], swizzled
    __shared__ __align__(16)   __bf16 p_c[4][2048];     // per-wave P, raw C-layout

    const int lane = threadIdx.x & 63;
    const int w    = threadIdx.x >> 6;
    const int quad = lane >> 4;
    const int l16  = lane & 15;
    const int bh    = blockIdx.y;
    const int qbase = blockIdx.x * 128 + w * 32;

    const __bf16* qp = q_ws + (long)bh * S * DK;
    const __bf16* kp = k_ws + (long)bh * S * DK;
    const __bf16* vp = v_ws + (long)bh * DK * S;   // [DK][S]

    // staging lane decomposition: 8 rows x 8 chunks(16B) per wave-issue
    const int sr  = lane >> 3;
    const int sc  = lane & 7;
    const int scs = sc ^ sr;            // swizzled SOURCE chunk

    // Q A-frags, loaded once (A[m=l16][k=quad*8+j])
    bf16x8 aq[2][2];
    #pragma unroll
    for (int mt = 0; mt < 2; mt++)
        #pragma unroll
        for (int ks = 0; ks < 2; ks++)
            aq[mt][ks] = *reinterpret_cast<const bf16x8*>(
                qp + (long)(qbase + mt * 16 + l16) * DK + ks * 32 + quad * 8);

    bf16x8 vone;
    #pragma unroll
    for (int j = 0; j < 8; j++) vone[j] = (__bf16)1.0f;

    f32x4 o[2][4];
    #pragma unroll
    for (int i = 0; i < 2; i++)
        #pragma unroll
        for (int j = 0; j < 4; j++) o[i][j] = f32x4{0.f, 0.f, 0.f, 0.f};
    f32x4 ls[2] = {f32x4{0.f, 0.f, 0.f, 0.f}, f32x4{0.f, 0.f, 0.f, 0.f}};

    // P read base: slot=((mt*4+(l16&3))*4 + ks*2 + (quad>>1)), entry=(l16>>2)*16+(quad&1)*8
    const int prd = (l16 & 3) * 256 + (quad >> 1) * 64 + (l16 >> 2) * 16 + (quad & 1) * 8;

    // prefetch tile 0 into buffer 0
    #pragma unroll
    for (int i = 0; i < 2; i++) {
        const int row = i * 32 + w * 8;                       // wave-uniform
        async16(&Ks[0][row * 64], kp + (long)(row + sr) * DK + scs * 8);
        async16(&Vs[0][row * 64], vp + (long)(row + sr) * S + scs * 8);
    }

    for (int it = 0; it < S / 64; it++) {
        const int cur = it & 1;
        __syncthreads();   // drains vmcnt(0): tile cur staged; prev reads done

        if (it + 1 < S / 64) {
            const int kt1 = (it + 1) * 64;
            #pragma unroll
            for (int i = 0; i < 2; i++) {
                const int row = i * 32 + w * 8;
                async16(&Ks[cur ^ 1][row * 64], kp + (long)(kt1 + row + sr) * DK + scs * 8);
                async16(&Vs[cur ^ 1][row * 64], vp + (long)(row + sr) * S + kt1 + scs * 8);
            }
        }

        // ---- S = Q K^T ----
        f32x4 sacc[2][4];
        #pragma unroll
        for (int i = 0; i < 2; i++)
            #pragma unroll
            for (int j = 0; j < 4; j++) sacc[i][j] = f32x4{0.f, 0.f, 0.f, 0.f};
        #pragma unroll
        for (int ks = 0; ks < 2; ks++) {
            bf16x8 bk[4];
            #pragma unroll
            for (int nt = 0; nt < 4; nt++)
                bk[nt] = *reinterpret_cast<const bf16x8*>(
                    &Ks[cur][(nt * 16 + l16) * 64 + ((ks * 4 + quad) ^ (l16 & 7)) * 8]);
            #pragma unroll
            for (int mt = 0; mt < 2; mt++)
                #pragma unroll
                for (int nt = 0; nt < 4; nt++)
                    sacc[mt][nt] = __builtin_amdgcn_mfma_f32_16x16x32_bf16(
                        aq[mt][ks], bk[nt], sacc[mt][nt], 0, 0, 0);
        }
        // ---- P = exp(S) -> per-wave LDS in raw C-layout (conflict-free) ----
        #pragma unroll
        for (int mt = 0; mt < 2; mt++)
            #pragma unroll
            for (int r = 0; r < 4; r++)
                #pragma unroll
                for (int nt = 0; nt < 4; nt++)
                    p_c[w][((mt * 4 + r) * 4 + nt) * 64 + lane] =
                        (__bf16)__expf(sacc[mt][nt][r]);
        // ---- O += P V ; l += P * ones ----
        #pragma unroll
        for (int ks = 0; ks < 2; ks++) {
            bf16x8 ap[2];
            #pragma unroll
            for (int mt = 0; mt < 2; mt++)
                ap[mt] = *reinterpret_cast<const bf16x8*>(
                    &p_c[w][prd + mt * 1024 + ks * 128]);
            bf16x8 bv[4];
            #pragma unroll
            for (int nd = 0; nd < 4; nd++)
                bv[nd] = *reinterpret_cast<const bf16x8*>(
                    &Vs[cur][(nd * 16 + l16) * 64 + ((ks * 4 + quad) ^ (l16 & 7)) * 8]);
            #pragma unroll
            for (int mt = 0; mt < 2; mt++) {
                ls[mt] = __builtin_amdgcn_mfma_f32_16x16x32_bf16(ap[mt], vone, ls[mt], 0, 0, 0);
                #pragma unroll
                for (int nd = 0; nd < 4; nd++)
                    o[mt][nd] = __builtin_amdgcn_mfma_f32_16x16x32_bf16(
                        ap[mt], bv[nd], o[mt][nd], 0, 0, 0);
            }
        }
    }

    // ---- epilogue: out[b][s][h*64+d] = O / l ----
    const int b = bh >> 4, h = bh & 15;
    #pragma unroll
    for (int mt = 0; mt < 2; mt++) {
        #pragma unroll
        for (int r = 0; r < 4; r++) {
            const float inv = 1.0f / ls[mt][r];
            const int srow = qbase + mt * 16 + quad * 4 + r;
            #pragma unroll
            for (int nd = 0; nd < 4; nd++)
                out[(long)(b * S + srow) * E + h * DK + nd * 16 + l16] = o[mt][nd][r] * inv;
        }
    }
}

// -------- fallback proj (direct fp32 loads, used only if ws too small) --------
__device__ inline bf16x8 cvt_frag(const float* __restrict__ p) {
    float4 f0 = *reinterpret_cast<const float4*>(p);
    float4 f1 = *reinterpret_cast<const float4*>(p + 4);
    bf16x8 r;
    r[0] = (__bf16)f0.x; r[1] = (__bf16)f0.y; r[2] = (__bf16)f0.z; r[3] = (__bf16)f0.w;
    r[4] = (__bf16)f1.x; r[5] = (__bf16)f1.y; r[6] = (__bf16)f1.z; r[7] = (__bf16)f1.w;
    return r;
}
template <int MODE>
__global__ __launch_bounds__(256, 2)
void proj_kernel(const float* __restrict__ x, const float* __restrict__ W,
                 const float* __restrict__ theta, __bf16* __restrict__ out) {
    const int lane = threadIdx.x & 63;
    const int w    = threadIdx.x >> 6;
    const int quad = lane >> 4;
    const int l16  = lane & 15;
    const int mbase = blockIdx.y * 128 + w * 32;
    const int nbase = blockIdx.x * 128;
    f32x4 acc[2][8];
    #pragma unroll
    for (int i = 0; i < 2; i++)
        #pragma unroll
        for (int j = 0; j < 8; j++) acc[i][j] = f32x4{0.f, 0.f, 0.f, 0.f};
    float th[4];
    if (MODE == 2) {
        #pragma unroll
        for (int j = 0; j < 4; j++) th[j] = theta[j * 16 + l16];
    }
    for (int kk = 0; kk < E; kk += 32) {
        bf16x8 a[2], b[8];
        #pragma unroll
        for (int mt = 0; mt < 2; mt++)
            a[mt] = cvt_frag(x + (long)(mbase + mt * 16 + l16) * E + kk + quad * 8);
        #pragma unroll
        for (int nt = 0; nt < 8; nt++)
            b[nt] = cvt_frag(W + (long)(nbase + nt * 16 + l16) * E + kk + quad * 8);
        #pragma unroll
        for (int mt = 0; mt < 2; mt++)
            #pragma unroll
            for (int nt = 0; nt < 8; nt++)
                acc[mt][nt] = __builtin_amdgcn_mfma_f32_16x16x32_bf16(a[mt], b[nt], acc[mt][nt], 0, 0, 0);
    }
    #pragma unroll
    for (int mt = 0; mt < 2; mt++) {
        const int row0 = mbase + mt * 16 + quad * 4;
        #pragma unroll
        for (int nt = 0; nt < 8; nt++) {
            const int col = nbase + nt * 16 + l16;
            const int h = col >> 6, d = col & 63;
            #pragma unroll
            for (int r = 0; r < 4; r++) {
                const int row = row0 + r;
                const int bb = row >> 11, s = row & 2047;
                float v = acc[mt][nt][r];
                if (MODE == 2) v = cosf(v + th[nt & 3]) * 0.125f;
                long idx;
                if (MODE == 1) idx = ((long)(bb * H + h) * DK + d) * S + s;
                else           idx = ((long)(bb * H + h) * S + s) * DK + d;
                out[idx] = (__bf16)v;
            }
        }
    }
}

extern "C" void kernel_launch(void* const* d_in, const int* in_sizes, int n_in,
                              void* d_out, int out_size, void* d_ws, size_t ws_size,
                              hipStream_t stream) {
    const float* x     = (const float*)d_in[0];
    const float* Wk    = (const float*)d_in[1];
    const float* Wv    = (const float*)d_in[2];
    const float* Wq    = (const float*)d_in[3];
    const float* theta = (const float*)d_in[4];
    float* out = (float*)d_out;

    // ws: kvq[3*RSZ: K | V^T | Q] | xb[M*E] | wall[N3*E]
    __bf16* kvq  = (__bf16*)d_ws;
    __bf16* xb   = kvq + 3 * RSZ;
    __bf16* wall = xb + (long)M * E;
    __bf16* k_ws = kvq;
    __bf16* v_t  = kvq + RSZ;
    __bf16* q_ws = kvq + 2 * RSZ;

    const size_t need = (3 * RSZ + (long)M * E + (long)N3 * E) * 2;
    dim3 blk(256);
    if (ws_size >= need) {
        cvt_kernel<<<dim3(7168), blk, 0, stream>>>(x, Wk, Wv, Wq, xb, wall);
        qkv_gemm<<<dim3(N3 / 128, M / 128), blk, 0, stream>>>(xb, wall, theta, kvq);
    } else {
        dim3 gp(E / 128, M / 128);
        proj_kernel<0><<<gp, blk, 0, stream>>>(x, Wk, nullptr, k_ws);
        proj_kernel<1><<<gp, blk, 0, stream>>>(x, Wv, nullptr, v_t);
        proj_kernel<2><<<gp, blk, 0, stream>>>(x, Wq, theta, q_ws);
    }

    attn_kernel<<<dim3(S / 128, B * H), blk, 0, stream>>>(q_ws, k_ws, v_t, out);
}

// Round 6
// 180.088 us; speedup vs baseline: 3.0930x; 1.0327x over previous
//
#include <hip/hip_runtime.h>
#include <hip/hip_bf16.h>

// Problem constants
constexpr int B  = 2;
constexpr int S  = 2048;
constexpr int E  = 1024;
constexpr int H  = 16;
constexpr int DK = 64;
constexpr int M  = B * S;            // 4096 rows of x
constexpr int N3 = 3 * E;            // stacked [Wk; Wv; Wq]
constexpr long RSZ = (long)B * H * S * DK;  // one output region (4.19M elems)

using bf16x8 = __attribute__((ext_vector_type(8))) __bf16;
using bf16x4 = __attribute__((ext_vector_type(4))) __bf16;
using f32x4  = __attribute__((ext_vector_type(4))) float;

// async global->LDS, 16B/lane; LDS base wave-uniform, lane i lands at +i*16 B.
__device__ __forceinline__ void async16(__bf16* lds, const __bf16* g) {
    __builtin_amdgcn_global_load_lds(
        (const __attribute__((address_space(1))) void*)g,
        (__attribute__((address_space(3))) void*)lds, 16, 0, 0);
}

// ---------------- cvt: x and stacked W's -> bf16 ----------------
__global__ __launch_bounds__(256)
void cvt_kernel(const float* __restrict__ x, const float* __restrict__ Wk,
                const float* __restrict__ Wv, const float* __restrict__ Wq,
                __bf16* __restrict__ xb, __bf16* __restrict__ wall) {
    const long e = ((long)blockIdx.x * 256 + threadIdx.x) * 4;
    const float* src;
    __bf16* dst;
    if (e < (long)M * E) { src = x + e; dst = xb + e; }
    else {
        const long e2 = e - (long)M * E;
        const int which = (int)(e2 >> 20);
        const long off  = e2 & ((1L << 20) - 1);
        src = (which == 0 ? Wk : which == 1 ? Wv : Wq) + off;
        dst = wall + e2;
    }
    float4 f = *reinterpret_cast<const float4*>(src);
    bf16x4 o;
    o[0] = (__bf16)f.x; o[1] = (__bf16)f.y; o[2] = (__bf16)f.z; o[3] = (__bf16)f.w;
    *reinterpret_cast<bf16x4*>(dst) = o;
}

// ---------------- fused QKV GEMM v2 (unchanged from R5) ----------------
__global__ __launch_bounds__(256, 3)
void qkv_gemm(const __bf16* __restrict__ xb, const __bf16* __restrict__ wall,
              const float* __restrict__ theta, __bf16* __restrict__ kvq) {
    __shared__ __align__(1024) __bf16 smem[4 * 128 * 32];   // As0|As1|Bs0|Bs1 = 32 KB
    __bf16* tile = smem;                                    // epilogue alias: 128x128

    const int t    = threadIdx.x;
    const int lane = t & 63;
    const int w    = t >> 6;
    const int quad = lane >> 4;
    const int l16  = lane & 15;
    const int wm   = w >> 1, wn = w & 1;      // 2x2 wave grid, 64x64 each
    const int mbase = blockIdx.y * 128;
    const int nbase = blockIdx.x * 128;

    f32x4 acc[4][4];
    #pragma unroll
    for (int i = 0; i < 4; i++)
        #pragma unroll
        for (int j = 0; j < 4; j++)
            acc[i][j] = f32x4{0.f, 0.f, 0.f, 0.f};

    const int srow = lane >> 2;
    const int srcc = (lane & 3) ^ ((lane >> 3) & 3);
    const __bf16* ga = xb   + (long)(mbase + srow) * E + srcc * 8;
    const __bf16* gb = wall + (long)(nbase + srow) * E + srcc * 8;

    const int csw = (l16 >> 1) & 3;

    #pragma unroll
    for (int c = 0; c < 2; c++) {
        async16(smem +        (c * 64 + w * 16) * 32, ga + (long)(c * 64 + w * 16) * E);
        async16(smem + 8192 + (c * 64 + w * 16) * 32, gb + (long)(c * 64 + w * 16) * E);
    }

    for (int it = 0; it < E / 32; it++) {
        const int cur = it & 1;
        __syncthreads();

        if (it + 1 < E / 32) {
            const int kk1 = (it + 1) * 32;
            #pragma unroll
            for (int c = 0; c < 2; c++) {
                async16(smem + (cur ^ 1) * 4096 +        (c * 64 + w * 16) * 32,
                        ga + (long)(c * 64 + w * 16) * E + kk1);
                async16(smem + (cur ^ 1) * 4096 + 8192 + (c * 64 + w * 16) * 32,
                        gb + (long)(c * 64 + w * 16) * E + kk1);
            }
        }

        const __bf16* Asb = smem + cur * 4096;
        const __bf16* Bsb = smem + cur * 4096 + 8192;
        bf16x8 a[4], b[4];
        #pragma unroll
        for (int i = 0; i < 4; i++)
            a[i] = *reinterpret_cast<const bf16x8*>(
                &Asb[(wm * 64 + i * 16 + l16) * 32 + (quad ^ csw) * 8]);
        #pragma unroll
        for (int j = 0; j < 4; j++)
            b[j] = *reinterpret_cast<const bf16x8*>(
                &Bsb[(wn * 64 + j * 16 + l16) * 32 + (quad ^ csw) * 8]);
        #pragma unroll
        for (int i = 0; i < 4; i++)
            #pragma unroll
            for (int j = 0; j < 4; j++)
                acc[i][j] = __builtin_amdgcn_mfma_f32_16x16x32_bf16(a[i], b[j], acc[i][j], 0, 0, 0);
    }

    const int region = nbase >> 10;           // block-uniform 0=K 1=V 2=Q
    const int bb = mbase >> 11;
    if (region == 1) {
        __syncthreads();
        #pragma unroll
        for (int i = 0; i < 4; i++) {
            const int cchunk = wm * 8 + i * 2 + (quad >> 1);
            #pragma unroll
            for (int j = 0; j < 4; j++) {
                const int cirb = wn * 64 + j * 16 + l16;
                const int cs = cchunk ^ l16;
                bf16x4 pk;
                #pragma unroll
                for (int r = 0; r < 4; r++) pk[r] = (__bf16)acc[i][j][r];
                *reinterpret_cast<bf16x4*>(&tile[cirb * 128 + cs * 8 + (quad & 1) * 4]) = pk;
            }
        }
        __syncthreads();
        const int h0 = (nbase & 1023) >> 6;
        __bf16* vt = kvq + RSZ;               // V^T region: [B,H,DK,S]
        #pragma unroll
        for (int p = 0; p < 8; p++) {
            const int dcol = p * 16 + (t >> 4);
            const int lc = t & 15;
            const int cs2 = lc ^ (dcol & 15);
            bf16x8 vv = *reinterpret_cast<const bf16x8*>(&tile[dcol * 128 + cs2 * 8]);
            const int hh = h0 + (dcol >> 6), d = dcol & 63;
            *reinterpret_cast<bf16x8*>(
                &vt[((long)(bb * H + hh) * DK + d) * S + (mbase & 2047) + lc * 8]) = vv;
        }
    } else {
        __bf16* dst = kvq + (region == 2 ? 2 * RSZ : 0);
        float th[4];
        if (region == 2) {
            #pragma unroll
            for (int j = 0; j < 4; j++) th[j] = theta[j * 16 + l16];
        }
        #pragma unroll
        for (int i = 0; i < 4; i++) {
            const int row0 = mbase + wm * 64 + i * 16 + quad * 4;
            #pragma unroll
            for (int j = 0; j < 4; j++) {
                const int cir = (nbase & 1023) + wn * 64 + j * 16 + l16;
                const int h = cir >> 6, d = cir & 63;
                #pragma unroll
                for (int r = 0; r < 4; r++) {
                    const int s = (row0 + r) & 2047;
                    float v = acc[i][j][r];
                    if (region == 2) v = cosf(v + th[j]) * 0.125f;  // fold 1/sqrt(DK)
                    dst[((long)(bb * H + h) * S + s) * DK + d] = (__bf16)v;
                }
            }
        }
    }
}

// ---------------- attention v5 ----------------
// 1024 blocks (XCD-swizzled id -> 4 bh per XCD => K/V set 2MB < 4MB L2), 4
// waves x 16 q-rows. KT=32 keys/iter, double-buffered 21 KB LDS -> 4 blocks/CU
// (16 waves/CU). P buffer stride 40 (non-pow2: rows spread banks; pow2 strides
// proven 8-way in R5). Bounded scores (|q|<=1/8) => no max-tracking (R1-R5).
__global__ __launch_bounds__(256, 4)
void attn_kernel(const __bf16* __restrict__ q_ws, const __bf16* __restrict__ k_ws,
                 const __bf16* __restrict__ v_ws, float* __restrict__ out) {
    __shared__ __align__(1024) __bf16 Ks[2][32 * 64];   // [key][d]   4 KB each
    __shared__ __align__(1024) __bf16 Vs[2][64 * 32];   // [d][key]   4 KB each
    __shared__ __align__(16)   __bf16 p_lds[4][16][40]; // per-wave P, stride 40

    const int lane = threadIdx.x & 63;
    const int w    = threadIdx.x >> 6;
    const int quad = lane >> 4;
    const int l16  = lane & 15;

    // XCD swizzle: id = 32*qtile + 8*m + c ; bh = c + 8*m (4 bh per id%8 class)
    const int id    = blockIdx.x;
    const int bh    = (id & 7) + 8 * ((id >> 3) & 3);
    const int qbase = (id >> 5) * 64 + w * 16;

    const __bf16* qp = q_ws + (long)bh * S * DK;
    const __bf16* kp = k_ws + (long)bh * S * DK;
    const __bf16* vp = v_ws + (long)bh * DK * S;   // [DK][S]

    // K staging: wave w covers keys w*8..+8; lane: sr=key offset, sc=16B chunk of d
    const int sr  = lane >> 3;
    const int sc  = lane & 7;
    const int scs = sc ^ sr;                       // swizzled source chunk
    // V staging: wave w covers d rows w*16..+16; lane: vr=d offset, vc=8-key chunk
    const int vr  = lane >> 2;
    const int vc  = lane & 3;
    const int vcs = vc ^ (vr & 3);

    // Q A-frags, loaded once (A[m=l16][k=quad*8+j])
    bf16x8 aq[2];
    #pragma unroll
    for (int ks = 0; ks < 2; ks++)
        aq[ks] = *reinterpret_cast<const bf16x8*>(
            qp + (long)(qbase + l16) * DK + ks * 32 + quad * 8);

    bf16x8 vone;
    #pragma unroll
    for (int j = 0; j < 8; j++) vone[j] = (__bf16)1.0f;

    f32x4 o[4];
    #pragma unroll
    for (int j = 0; j < 4; j++) o[j] = f32x4{0.f, 0.f, 0.f, 0.f};
    f32x4 ls = f32x4{0.f, 0.f, 0.f, 0.f};

    // prefetch tile 0 into buffer 0
    async16(&Ks[0][(w * 8) * 64], kp + (long)(w * 8 + sr) * DK + scs * 8);
    async16(&Vs[0][(w * 16) * 32], vp + (long)(w * 16 + vr) * S + vcs * 8);

    for (int it = 0; it < S / 32; it++) {
        const int cur = it & 1;
        __syncthreads();   // drains vmcnt(0): tile cur staged; prev reads done

        if (it + 1 < S / 32) {
            const int kt1 = (it + 1) * 32;
            async16(&Ks[cur ^ 1][(w * 8) * 64],
                    kp + (long)(kt1 + w * 8 + sr) * DK + scs * 8);
            async16(&Vs[cur ^ 1][(w * 16) * 32],
                    vp + (long)(w * 16 + vr) * S + kt1 + vcs * 8);
        }

        // ---- S = Q K^T  (16 q-rows x 32 keys) ----
        f32x4 sacc[2];
        sacc[0] = f32x4{0.f, 0.f, 0.f, 0.f};
        sacc[1] = f32x4{0.f, 0.f, 0.f, 0.f};
        #pragma unroll
        for (int ks = 0; ks < 2; ks++) {
            #pragma unroll
            for (int nt = 0; nt < 2; nt++) {
                bf16x8 bk = *reinterpret_cast<const bf16x8*>(
                    &Ks[cur][(nt * 16 + l16) * 64 + ((ks * 4 + quad) ^ (l16 & 7)) * 8]);
                sacc[nt] = __builtin_amdgcn_mfma_f32_16x16x32_bf16(aq[ks], bk, sacc[nt], 0, 0, 0);
            }
        }
        // ---- P = exp(S) -> per-wave LDS ----
        #pragma unroll
        for (int nt = 0; nt < 2; nt++)
            #pragma unroll
            for (int r = 0; r < 4; r++)
                p_lds[w][quad * 4 + r][nt * 16 + l16] = (__bf16)__expf(sacc[nt][r]);
        // ---- O += P V ; l += P * ones ----
        bf16x8 ap = *reinterpret_cast<const bf16x8*>(&p_lds[w][l16][quad * 8]);
        ls = __builtin_amdgcn_mfma_f32_16x16x32_bf16(ap, vone, ls, 0, 0, 0);
        #pragma unroll
        for (int nd = 0; nd < 4; nd++) {
            bf16x8 bv = *reinterpret_cast<const bf16x8*>(
                &Vs[cur][(nd * 16 + l16) * 32 + (quad ^ (l16 & 3)) * 8]);
            o[nd] = __builtin_amdgcn_mfma_f32_16x16x32_bf16(ap, bv, o[nd], 0, 0, 0);
        }
    }

    // ---- epilogue: out[b][s][h*64+d] = O / l ----
    const int b = bh >> 4, h = bh & 15;
    #pragma unroll
    for (int r = 0; r < 4; r++) {
        const float inv = 1.0f / ls[r];
        const int srow = qbase + quad * 4 + r;
        #pragma unroll
        for (int nd = 0; nd < 4; nd++)
            out[(long)(b * S + srow) * E + h * DK + nd * 16 + l16] = o[nd][r] * inv;
    }
}

// -------- fallback proj (direct fp32 loads, used only if ws too small) --------
__device__ inline bf16x8 cvt_frag(const float* __restrict__ p) {
    float4 f0 = *reinterpret_cast<const float4*>(p);
    float4 f1 = *reinterpret_cast<const float4*>(p + 4);
    bf16x8 r;
    r[0] = (__bf16)f0.x; r[1] = (__bf16)f0.y; r[2] = (__bf16)f0.z; r[3] = (__bf16)f0.w;
    r[4] = (__bf16)f1.x; r[5] = (__bf16)f1.y; r[6] = (__bf16)f1.z; r[7] = (__bf16)f1.w;
    return r;
}
template <int MODE>
__global__ __launch_bounds__(256, 2)
void proj_kernel(const float* __restrict__ x, const float* __restrict__ W,
                 const float* __restrict__ theta, __bf16* __restrict__ out) {
    const int lane = threadIdx.x & 63;
    const int w    = threadIdx.x >> 6;
    const int quad = lane >> 4;
    const int l16  = lane & 15;
    const int mbase = blockIdx.y * 128 + w * 32;
    const int nbase = blockIdx.x * 128;
    f32x4 acc[2][8];
    #pragma unroll
    for (int i = 0; i < 2; i++)
        #pragma unroll
        for (int j = 0; j < 8; j++) acc[i][j] = f32x4{0.f, 0.f, 0.f, 0.f};
    float th[4];
    if (MODE == 2) {
        #pragma unroll
        for (int j = 0; j < 4; j++) th[j] = theta[j * 16 + l16];
    }
    for (int kk = 0; kk < E; kk += 32) {
        bf16x8 a[2], b[8];
        #pragma unroll
        for (int mt = 0; mt < 2; mt++)
            a[mt] = cvt_frag(x + (long)(mbase + mt * 16 + l16) * E + kk + quad * 8);
        #pragma unroll
        for (int nt = 0; nt < 8; nt++)
            b[nt] = cvt_frag(W + (long)(nbase + nt * 16 + l16) * E + kk + quad * 8);
        #pragma unroll
        for (int mt = 0; mt < 2; mt++)
            #pragma unroll
            for (int nt = 0; nt < 8; nt++)
                acc[mt][nt] = __builtin_amdgcn_mfma_f32_16x16x32_bf16(a[mt], b[nt], acc[mt][nt], 0, 0, 0);
    }
    #pragma unroll
    for (int mt = 0; mt < 2; mt++) {
        const int row0 = mbase + mt * 16 + quad * 4;
        #pragma unroll
        for (int nt = 0; nt < 8; nt++) {
            const int col = nbase + nt * 16 + l16;
            const int h = col >> 6, d = col & 63;
            #pragma unroll
            for (int r = 0; r < 4; r++) {
                const int row = row0 + r;
                const int bb = row >> 11, s = row & 2047;
                float v = acc[mt][nt][r];
                if (MODE == 2) v = cosf(v + th[nt & 3]) * 0.125f;
                long idx;
                if (MODE == 1) idx = ((long)(bb * H + h) * DK + d) * S + s;
                else           idx = ((long)(bb * H + h) * S + s) * DK + d;
                out[idx] = (__bf16)v;
            }
        }
    }
}

extern "C" void kernel_launch(void* const* d_in, const int* in_sizes, int n_in,
                              void* d_out, int out_size, void* d_ws, size_t ws_size,
                              hipStream_t stream) {
    const float* x     = (const float*)d_in[0];
    const float* Wk    = (const float*)d_in[1];
    const float* Wv    = (const float*)d_in[2];
    const float* Wq    = (const float*)d_in[3];
    const float* theta = (const float*)d_in[4];
    float* out = (float*)d_out;

    // ws: kvq[3*RSZ: K | V^T | Q] | xb[M*E] | wall[N3*E]
    __bf16* kvq  = (__bf16*)d_ws;
    __bf16* xb   = kvq + 3 * RSZ;
    __bf16* wall = xb + (long)M * E;
    __bf16* k_ws = kvq;
    __bf16* v_t  = kvq + RSZ;
    __bf16* q_ws = kvq + 2 * RSZ;

    const size_t need = (3 * RSZ + (long)M * E + (long)N3 * E) * 2;
    dim3 blk(256);
    if (ws_size >= need) {
        cvt_kernel<<<dim3(7168), blk, 0, stream>>>(x, Wk, Wv, Wq, xb, wall);
        qkv_gemm<<<dim3(N3 / 128, M / 128), blk, 0, stream>>>(xb, wall, theta, kvq);
    } else {
        dim3 gp(E / 128, M / 128);
        proj_kernel<0><<<gp, blk, 0, stream>>>(x, Wk, nullptr, k_ws);
        proj_kernel<1><<<gp, blk, 0, stream>>>(x, Wv, nullptr, v_t);
        proj_kernel<2><<<gp, blk, 0, stream>>>(x, Wq, theta, q_ws);
    }

    attn_kernel<<<dim3(1024), blk, 0, stream>>>(q_ws, k_ws, v_t, out);
}